// Round 4
// baseline (2243.777 us; speedup 1.0000x reference)
//
#include <hip/hip_runtime.h>

// Greedy NMS: keep[i] = !any(keep[j] for j in knn[i] if j < i)
//
// Round-16: repair R15's CHUNK=4096 geometry. R15 regressed (775 us vs R13's
// 433) because ilr[4][8] SPILLED TO SCRATCH (VGPR_Count stayed 52 == R13's --
// impossible for the added working set), putting ~128 scratch loads per
// fixed-point iteration on the critical path (+15 us/hop, matching measured).
// Fixes:
//   - __launch_bounds__(1024, 4): LDS (118KB) already forces 1 block/CU ->
//     4 waves/SIMD -> allocator may use 128 VGPRs. Use that headroom.
//   - intra-pred lists PACKED as u16 pairs in u32 (ilp[4][4] = 16 VGPRs,
//     compile-time indices only); rowq recomputed on the fly.
//   - barrier-free direct publish: each wave stores its own two 32-row u64
//     words (lanes 0/32 of the ballot). Publish barrier + bw LDS deleted.
//   - all wait-path spins keep the R13-validated s_sleep form (R14 lesson:
//     pure busy-poll congested the LLC and starved producer stores).
// Geometry: CHUNK=4096 (QRT=4), NCH=37, WCH=2 (8192-row window), ICAP=8,
// ECAP=12, in-band valid bits (bit32), 1 barrier/iter fixed-point.
//
// Output encoding (validated round 4): INT32.
//   d_out[0..M)        : kept flags, 1 / 0
//   d_out[M..M+M*64)   : kept_knn, idx or 150000 (tail doubles as u64 word
//                        scratch, owned by block 36 which never publishes)
// d_ws[0..3]: progress counter (zeroed by init kernel each call)

#define M_ROWS 150000
#define KNN    64
#define BLK    1024
#define QRT    4
#define CHUNK  (BLK * QRT)                        // 4096
#define NCH    ((M_ROWS + CHUNK - 1) / CHUNK)     // 37
#define ICAP   8
#define ECAP   12
#define WCH    2                                  // exl window, chunks (8192 rows)
#define W64PC  (CHUNK / 32)                       // 128 published u64 words/chunk
#define LMW    (((NCH - 1) * CHUNK) / 32)         // 4608 u32 mirror words
#define NBMG   ((NCH - 1) * W64PC)                // 4608 published u64 words
#define OUT_INTS (M_ROWS + M_ROWS * KNN)
#define BMG_INT_OFF (OUT_INTS - NBMG * 2)         // 8B-aligned; rows >= 149856
#define VALIDB (1ull << 32)

__global__ void init_ws_kernel(unsigned int* progress, int* out) {
  const int i = blockIdx.x * blockDim.x + threadIdx.x;
  unsigned long long* bmg64 = (unsigned long long*)(out + BMG_INT_OFF);
  if (i < NBMG) bmg64[i] = 0ull;                  // clear stale valid bits
  if (i == 0) *progress = 0u;
}

// reload a row and probe preds j in [lo, hi) against the LDS bitmask
__device__ __forceinline__ bool probe_reload(const int* __restrict__ rp,
                                             const unsigned int* lm,
                                             int lo, int hi) {
  bool s = false;
#pragma unroll
  for (int u = 0; u < 16; ++u) {
    int4 d = ((const int4*)rp)[u];
    int js[4] = {d.x, d.y, d.z, d.w};
#pragma unroll
    for (int m = 0; m < 4; ++m) {
      int j = js[m];
      if (j >= lo && j < hi && ((lm[j >> 5] >> (j & 31)) & 1u)) s = true;
    }
  }
  return s;
}

__global__ __launch_bounds__(BLK, 4) void nms_chain_kernel(
    const int* __restrict__ knn,
    int* __restrict__ out,
    unsigned int* __restrict__ progress)
{
  const int b    = blockIdx.x;
  const int t    = threadIdx.x;
  const int base = b * CHUNK;
  const int winb = (b > WCH) ? (base - WCH * CHUNK) : 0;   // exl window base

  unsigned long long* bmg64 = (unsigned long long*)(out + BMG_INT_OFF);

  __shared__ unsigned char      st[CHUNK];        // 0 unk, 1 kept, 2 supp
  __shared__ unsigned short     exl[ECAP][CHUNK]; // TRANSPOSED: conflict-free
  __shared__ unsigned int       lm[LMW];          // mirrored keep bits
  __shared__ unsigned int       sh_p;
  __shared__ int                flags[2];

  bool vq[QRT], ovf[QRT], eovf[QRT], supp[QRT];
  int  ic[QRT], ec[QRT];
  unsigned int ilp[QRT][ICAP / 2];                // packed u16 pairs: 16 VGPRs

#pragma unroll
  for (int q = 0; q < QRT; ++q) {
    vq[q]   = (base + q * BLK + t) < M_ROWS;
    ic[q] = ec[q] = 0;
    ovf[q] = eovf[q] = supp[q] = false;
#pragma unroll
    for (int x = 0; x < ICAP / 2; ++x) ilp[q][x] = 0u;
  }

  // ---- classification: intra lists (packed regs) + window lists (LDS) ----
#pragma unroll
  for (int q = 0; q < QRT; ++q) {
    if (!vq[q]) continue;
    const int o   = q * BLK + t;
    const int row = base + o;
    const int* rp = knn + (long long)row * KNN;
#pragma unroll
    for (int u = 0; u < 16; ++u) {
      int4 d = ((const int4*)rp)[u];
      int js[4] = {d.x, d.y, d.z, d.w};
#pragma unroll
      for (int m = 0; m < 4; ++m) {
        int j = js[m];
        if (j < row) {                            // strict <: ref semantics
          if (j >= base) {
            const unsigned int v = (unsigned int)(j - base);
#pragma unroll
            for (int x = 0; x < ICAP; ++x)        // compile-time indices only
              if (ic[q] == x)
                ilp[q][x >> 1] = (x & 1)
                  ? ((ilp[q][x >> 1] & 0x0000ffffu) | (v << 16))
                  : ((ilp[q][x >> 1] & 0xffff0000u) | v);
            ++ic[q];
          } else if (j >= winb) {
            if (ec[q] < ECAP) exl[ec[q]][o] = (unsigned short)(j - winb);
            ++ec[q];
          }
          // j < winb: covered by the phase-1 reload probe
        }
      }
    }
  }
#pragma unroll
  for (int q = 0; q < QRT; ++q) {
    ovf[q]  = ic[q] > ICAP; if (ovf[q])  ic[q] = ICAP;
    eovf[q] = ec[q] > ECAP; if (eovf[q]) ec[q] = ECAP;
  }

  // ---- wait path ----
  int praw1 = 0, wcop = 0;
  if (b > WCH) {
    // phase 1: counter is only a trigger hint for the single forced reload
    if (t < 64) {
      int pr = 0;
      for (int spin = 0; spin < (1 << 22); ++spin) {
        pr = (int)__hip_atomic_load(progress, __ATOMIC_RELAXED,
                                    __HIP_MEMORY_SCOPE_AGENT);
        if (pr >= b - WCH) break;
        __builtin_amdgcn_s_sleep(2);
      }
      if (t == 0) sh_p = (unsigned int)pr;
    }
    __syncthreads();                              // sh_p visible
    praw1 = (int)sh_p; if (praw1 > b) praw1 = b;
    const int wt = praw1 * W64PC;
    for (int w = t; w < wt; w += BLK) {           // per-word valid-spin backstop
      unsigned long long v = __hip_atomic_load(&bmg64[w], __ATOMIC_RELAXED,
                                               __HIP_MEMORY_SCOPE_AGENT);
      int g1 = 0;
      while (!(v & VALIDB) && ++g1 < (1 << 22)) {
        __builtin_amdgcn_s_sleep(1);
        v = __hip_atomic_load(&bmg64[w], __ATOMIC_RELAXED,
                              __HIP_MEMORY_SCOPE_AGENT);
      }
      lm[w] = (unsigned int)v;
    }
    wcop = wt;
    __syncthreads();                              // lm visible
    const int lim = praw1 * CHUNK;
#pragma unroll
    for (int q = 0; q < QRT; ++q)
      if (vq[q])
        supp[q] = probe_reload(knn + (long long)(base + q * BLK + t) * KNN,
                               lm, 0, lim);
  }
  // phase 2: turn-wait == data arrival. Spin on predecessor words directly
  // (typically 256 new words -> waves 0-3 spin; others park at the barrier).
  if (b > 0 && wcop < b * W64PC) {
    const int wt = b * W64PC;
    for (int w = wcop + t; w < wt; w += BLK) {
      unsigned long long v = __hip_atomic_load(&bmg64[w], __ATOMIC_RELAXED,
                                               __HIP_MEMORY_SCOPE_AGENT);
      int g2 = 0;
      while (!(v & VALIDB) && ++g2 < (1 << 22)) {
        __builtin_amdgcn_s_sleep(1);
        v = __hip_atomic_load(&bmg64[w], __ATOMIC_RELAXED,
                              __HIP_MEMORY_SCOPE_AGENT);
      }
      lm[w] = (unsigned int)v;
    }
    __syncthreads();                              // lm complete
  }
  if (b > 0) {
    // window probes, unrolled + predicated (no break): loads pipeline
    const int pr1lim = praw1 * CHUNK;
#pragma unroll
    for (int q = 0; q < QRT; ++q) {
      if (!vq[q] || supp[q]) continue;
      const int o = q * BLK + t;
      const int n = ec[q];
      bool s = false;
#pragma unroll
      for (int x = 0; x < ECAP; ++x) {
        if (x < n) {
          int j = winb + (int)exl[x][o];
          s |= (j >= pr1lim) && (((lm[j >> 5] >> (j & 31)) & 1u) != 0u);
        }
      }
      if (s) supp[q] = true;
      if (!supp[q] && eovf[q])                    // dropped entries (rare)
        supp[q] = probe_reload(knn + (long long)(base + o) * KNN,
                               lm, winb, base);
    }
  }

  // ---- intra-chunk monotone fixed-point: ONE barrier per iteration ----
#pragma unroll
  for (int q = 0; q < QRT; ++q) {
    const int o = q * BLK + t;
    st[o] = (!vq[q] || supp[q]) ? (unsigned char)2
          : ((ic[q] == 0 && !ovf[q]) ? (unsigned char)1 : (unsigned char)0);
  }
  if (t == 0) { flags[0] = 0; flags[1] = 0; }
  __syncthreads();

  for (int it = 0; it < CHUNK; ++it) {
    bool un = false;
#pragma unroll
    for (int s = 0; s < 4; ++s) {                 // monotone: stale reads safe
      un = false;
#pragma unroll
      for (int q = 0; q < QRT; ++q) {
        const int o = q * BLK + t;
        if (st[o] == 0) {
          bool anyK = false, allD = true;
          if (!ovf[q]) {
#pragma unroll
            for (int x = 0; x < ICAP; ++x) {      // single-level LDS: st[reg]
              if (x < ic[q]) {
                const int idx = (x & 1) ? (int)(ilp[q][x >> 1] >> 16)
                                        : (int)(ilp[q][x >> 1] & 0xffffu);
                unsigned char v = st[idx];
                anyK |= (v == 1); allD &= (v != 0);
              }
            }
          } else {                                // rare: rescan from global
            const int row = base + o;
            const int* rp = knn + (long long)row * KNN;
#pragma unroll
            for (int k = 0; k < KNN; ++k) {
              int j = rp[k];
              if (j >= base && j < row) {
                unsigned char v = st[j - base];
                anyK |= (v == 1); allD &= (v != 0);
              }
            }
          }
          if (anyK) st[o] = 2; else if (allD) st[o] = 1;
          if (st[o] == 0) un = true;
        }
      }
    }
    if (t == 0) flags[(it + 1) & 1] = 0;          // pre-zero next slot
    if (un) flags[it & 1] = 1;                    // benign race
    __syncthreads();                              // st + flags visible
    if (flags[it & 1] == 0) break;
  }

  // ---- publish: DIRECT per-wave ballot stores (no barrier, no LDS) ----
  bool kq[QRT];
#pragma unroll
  for (int q = 0; q < QRT; ++q)
    kq[q] = vq[q] && (st[q * BLK + t] == 1);

  if (b < NCH - 1) {
    const int lane = t & 63;
#pragma unroll
    for (int q = 0; q < QRT; ++q) {
      unsigned long long ba = __ballot(kq[q]);    // rows base+q*1024+(t&~63)+lane
      const int g = b * W64PC + ((q * BLK + (t & ~63)) >> 5);
      if (lane == 0)
        __hip_atomic_store(&bmg64[g], (ba & 0xffffffffull) | VALIDB,
                           __ATOMIC_RELAXED, __HIP_MEMORY_SCOPE_AGENT);
      if (lane == 32)
        __hip_atomic_store(&bmg64[g + 1], (ba >> 32) | VALIDB,
                           __ATOMIC_RELAXED, __HIP_MEMORY_SCOPE_AGENT);
    }
  }
  if (t == 0)                                     // hint only; relaxed is fine
    __hip_atomic_store(progress, (unsigned int)(b + 1),
                       __ATOMIC_RELAXED, __HIP_MEMORY_SCOPE_AGENT);

  // ---- outputs (off the chain; block 36's knn overwrites dead scratch) ----
#pragma unroll
  for (int q = 0; q < QRT; ++q)
    if (vq[q]) out[base + q * BLK + t] = kq[q] ? 1 : 0;

#pragma unroll
  for (int q = 0; q < QRT; ++q) {
    if (!vq[q]) continue;
    const int row = base + q * BLK + t;
    const int* rp = knn + (long long)row * KNN;
    int* orow = out + M_ROWS + (long long)row * KNN;
    const bool k = kq[q];
#pragma unroll
    for (int u = 0; u < 16; ++u) {
      int4 d = ((const int4*)rp)[u];
      int4 o4;
      o4.x = k ? d.x : M_ROWS;
      o4.y = k ? d.y : M_ROWS;
      o4.z = k ? d.z : M_ROWS;
      o4.w = k ? d.w : M_ROWS;
      ((int4*)orow)[u] = o4;
    }
  }
}

extern "C" void kernel_launch(void* const* d_in, const int* in_sizes, int n_in,
                              void* d_out, int out_size, void* d_ws, size_t ws_size,
                              hipStream_t stream) {
  const int* knn = (const int*)d_in[1];
  int* out = (int*)d_out;
  unsigned int* progress = (unsigned int*)d_ws;

  init_ws_kernel<<<(NBMG + BLK - 1) / BLK, BLK, 0, stream>>>(progress, out);
  nms_chain_kernel<<<NCH, BLK, 0, stream>>>(knn, out, progress);
}

// Round 5
// 485.631 us; speedup vs baseline: 4.6203x; 4.6203x over previous
//
#include <hip/hip_runtime.h>

// Greedy NMS: keep[i] = !any(keep[j] for j in knn[i] if j < i)
//
// Round-17: revert to the validated R13 geometry (CHUNK=2048, QRT=2, NCH=74,
// WCH=4 — 433 us kernel). R15/R16 established that CHUNK=4096 is intrinsically
// bad: the phase-1 forced reload (CHUNK x 256B from global, L2-evicted) must
// hide under WCH hops of cover; halving WCH while doubling the reload leaks
// ~10-40 us/hop onto the chain (measured 21 us/hop R15, 59 R16 with publish
// jitter). R13's 0.5MB/4-hop ratio just barely hides it.
// Changes vs R13, confined to the post-wait endgame (~2 us/hop of 5.45):
//   - BARRIER-FREE SPIN FIXED-POINT: LDS is physically shared; the old
//     per-iteration block barrier served only the convergence-flag protocol.
//     Now: st init + one barrier, then each thread spins until its OWN rows
//     decide, via workgroup-scope relaxed atomic u8 loads/stores (blocks
//     compiler hoisting). Monotone 0->{1,2} makes stale reads safe. Chain
//     depth ~ e*n*p ~ 2.4 levels -> a few passes.
//   - PER-WAVE IMMEDIATE PUBLISH: each wave stores its 4 u64 words (ballot,
//     lanes 0/32) as soon as its own 128 rows are decided; no block barrier,
//     no bw LDS staging. Downstream per-word valid spins tolerate stagger.
//     progress hint kept conservative: one barrier, then t0 stores it.
//   - wait path, classification, il/exl structures: byte-identical to R13.
//
// Output encoding (validated round 4): INT32.
//   d_out[0..M)        : kept flags, 1 / 0
//   d_out[M..M+M*64)   : kept_knn, idx or 150000 (tail doubles as u64 word
//                        scratch, owned by block 73 which never publishes)
// d_ws[0..3]: progress counter (zeroed by init kernel each call)

#define M_ROWS 150000
#define KNN    64
#define BLK    1024
#define QRT    2
#define CHUNK  (BLK * QRT)                        // 2048
#define NCH    ((M_ROWS + CHUNK - 1) / CHUNK)     // 74
#define ICAP   6
#define ECAP   12
#define WCH    4                                  // exl window, chunks
#define W64PC  (CHUNK / 32)                       // 64 published u64 words/chunk
#define LMW    (((NCH - 1) * CHUNK) / 32)         // 4672 u32 mirror words
#define NBMG   ((NCH - 1) * W64PC)                // 4672 published u64 words
#define OUT_INTS (M_ROWS + M_ROWS * KNN)
#define BMG_INT_OFF (OUT_INTS - NBMG * 2)         // 8B-aligned; rows >= 149854
#define VALIDB (1ull << 32)

__global__ void init_ws_kernel(unsigned int* progress, int* out) {
  const int i = blockIdx.x * blockDim.x + threadIdx.x;
  unsigned long long* bmg64 = (unsigned long long*)(out + BMG_INT_OFF);
  if (i < NBMG) bmg64[i] = 0ull;                  // clear stale valid bits
  if (i == 0) *progress = 0u;
}

// reload a row and probe preds j in [lo, hi) against the LDS bitmask
__device__ __forceinline__ bool probe_reload(const int* __restrict__ rp,
                                             const unsigned int* lm,
                                             int lo, int hi) {
  bool s = false;
#pragma unroll
  for (int u = 0; u < 16; ++u) {
    int4 d = ((const int4*)rp)[u];
    int js[4] = {d.x, d.y, d.z, d.w};
#pragma unroll
    for (int m = 0; m < 4; ++m) {
      int j = js[m];
      if (j >= lo && j < hi && ((lm[j >> 5] >> (j & 31)) & 1u)) s = true;
    }
  }
  return s;
}

__global__ __launch_bounds__(BLK) void nms_chain_kernel(
    const int* __restrict__ knn,
    int* __restrict__ out,
    unsigned int* __restrict__ progress)
{
  const int b    = blockIdx.x;
  const int t    = threadIdx.x;
  const int base = b * CHUNK;
  const int winb = (b > WCH) ? (base - WCH * CHUNK) : 0;   // exl window base

  unsigned long long* bmg64 = (unsigned long long*)(out + BMG_INT_OFF);

  __shared__ unsigned char      st[CHUNK];        // 0 unk, 1 kept, 2 supp
  __shared__ unsigned short     il[ICAP][CHUNK];  // TRANSPOSED: conflict-free
  __shared__ unsigned short     exl[ECAP][CHUNK]; // TRANSPOSED: conflict-free
  __shared__ unsigned int       lm[LMW];          // mirrored keep bits
  __shared__ unsigned int       sh_p;

  int  rowq[QRT];
  bool vq[QRT], ovf[QRT], eovf[QRT], supp[QRT];
  int  ic[QRT], ec[QRT];

#pragma unroll
  for (int q = 0; q < QRT; ++q) {
    rowq[q] = base + q * BLK + t;
    vq[q]   = rowq[q] < M_ROWS;
    ic[q] = ec[q] = 0;
    ovf[q] = eovf[q] = supp[q] = false;
  }

  // ---- classification: intra-chunk + static-window pred lists ----
#pragma unroll
  for (int q = 0; q < QRT; ++q) {
    if (!vq[q]) continue;
    const int o   = q * BLK + t;
    const int row = rowq[q];
    const int* rp = knn + (long long)row * KNN;
#pragma unroll
    for (int u = 0; u < 16; ++u) {
      int4 d = ((const int4*)rp)[u];
      int js[4] = {d.x, d.y, d.z, d.w};
#pragma unroll
      for (int m = 0; m < 4; ++m) {
        int j = js[m];
        if (j < row) {                            // strict <: ref semantics
          if (j >= base) {
            if (ic[q] < ICAP) il[ic[q]][o] = (unsigned short)(j - base);
            ++ic[q];
          } else if (j >= winb) {
            if (ec[q] < ECAP) exl[ec[q]][o] = (unsigned short)(j - winb);
            ++ec[q];
          }
          // j < winb: covered by the phase-1 reload probe
        }
      }
    }
  }
#pragma unroll
  for (int q = 0; q < QRT; ++q) {
    ovf[q]  = ic[q] > ICAP; if (ovf[q])  ic[q] = ICAP;
    eovf[q] = ec[q] > ECAP; if (eovf[q]) ec[q] = ECAP;
  }

  // ---- pre-wait: read il lists back into registers (own writes; no barrier;
  //      full unroll -> compile-time indices -> stays in VGPRs) ----
  unsigned short ilr[QRT][ICAP];
#pragma unroll
  for (int q = 0; q < QRT; ++q)
#pragma unroll
    for (int x = 0; x < ICAP; ++x)
      ilr[q][x] = il[x][q * BLK + t];             // garbage beyond ic[q]: never used

  // ---- wait path (byte-identical to R13) ----
  int praw1 = 0, wcop = 0;
  if (b > WCH) {
    // phase 1: counter is only a trigger hint for the single forced reload
    if (t < 64) {
      int pr = 0;
      for (int spin = 0; spin < (1 << 22); ++spin) {
        pr = (int)__hip_atomic_load(progress, __ATOMIC_RELAXED,
                                    __HIP_MEMORY_SCOPE_AGENT);
        if (pr >= b - WCH) break;
        __builtin_amdgcn_s_sleep(2);
      }
      if (t == 0) sh_p = (unsigned int)pr;
    }
    __syncthreads();                              // sh_p visible
    praw1 = (int)sh_p; if (praw1 > b) praw1 = b;
    const int wt = praw1 * W64PC;
    for (int w = t; w < wt; w += BLK) {           // per-word valid-spin backstop
      unsigned long long v = __hip_atomic_load(&bmg64[w], __ATOMIC_RELAXED,
                                               __HIP_MEMORY_SCOPE_AGENT);
      int g1 = 0;
      while (!(v & VALIDB) && ++g1 < (1 << 22)) {
        __builtin_amdgcn_s_sleep(1);
        v = __hip_atomic_load(&bmg64[w], __ATOMIC_RELAXED,
                              __HIP_MEMORY_SCOPE_AGENT);
      }
      lm[w] = (unsigned int)v;
    }
    wcop = wt;
    __syncthreads();                              // lm visible
    const int lim = praw1 * CHUNK;
#pragma unroll
    for (int q = 0; q < QRT; ++q)
      if (vq[q])
        supp[q] = probe_reload(knn + (long long)rowq[q] * KNN, lm, 0, lim);
  }
  // phase 2: turn-wait == data arrival. Spin on predecessor words directly
  // (typically 256 new words -> waves 0-3 spin; others park at the barrier).
  if (b > 0 && wcop < b * W64PC) {
    const int wt = b * W64PC;
    for (int w = wcop + t; w < wt; w += BLK) {
      unsigned long long v = __hip_atomic_load(&bmg64[w], __ATOMIC_RELAXED,
                                               __HIP_MEMORY_SCOPE_AGENT);
      int g2 = 0;
      while (!(v & VALIDB) && ++g2 < (1 << 22)) {
        __builtin_amdgcn_s_sleep(1);
        v = __hip_atomic_load(&bmg64[w], __ATOMIC_RELAXED,
                              __HIP_MEMORY_SCOPE_AGENT);
      }
      lm[w] = (unsigned int)v;
    }
    __syncthreads();                              // lm complete
  }
  if (b > 0) {
    // window probes, unrolled + predicated (no break): loads pipeline
    const int pr1lim = praw1 * CHUNK;
#pragma unroll
    for (int q = 0; q < QRT; ++q) {
      if (!vq[q] || supp[q]) continue;
      const int o = q * BLK + t;
      const int n = ec[q];
      bool s = false;
#pragma unroll
      for (int x = 0; x < ECAP; ++x) {
        if (x < n) {
          int j = winb + (int)exl[x][o];
          s |= (j >= pr1lim) && (((lm[j >> 5] >> (j & 31)) & 1u) != 0u);
        }
      }
      if (s) supp[q] = true;
      if (!supp[q] && eovf[q])                    // dropped entries (rare)
        supp[q] = probe_reload(knn + (long long)rowq[q] * KNN, lm, winb, base);
    }
  }

  // ---- intra-chunk fixed-point: BARRIER-FREE SPIN ----
  // st is monotone (0 -> 1|2, written once, only by the owning thread).
  // LDS is physically shared across the CU; atomic(relaxed, workgroup) u8
  // ops pin the loads/stores in the loop (no hoisting). One barrier makes
  // the init values visible; after that, propagation is pure LDS latency.
  unsigned char myst[QRT];
#pragma unroll
  for (int q = 0; q < QRT; ++q) {
    myst[q] = (!vq[q] || supp[q]) ? (unsigned char)2
            : ((ic[q] == 0 && !ovf[q]) ? (unsigned char)1 : (unsigned char)0);
    __hip_atomic_store(&st[q * BLK + t], myst[q],
                       __ATOMIC_RELAXED, __HIP_MEMORY_SCOPE_WORKGROUP);
  }
  __syncthreads();                                // init visible to all waves

  bool undec = (myst[0] == 0) | (myst[1] == 0);
  for (int pass = 0; pass < (1 << 14) && undec; ++pass) {
    undec = false;
#pragma unroll
    for (int q = 0; q < QRT; ++q) {
      if (myst[q] != 0) continue;
      const int o = q * BLK + t;
      bool anyK = false, allD = true;
      if (!ovf[q]) {
#pragma unroll
        for (int x = 0; x < ICAP; ++x) {
          if (x < ic[q]) {
            unsigned char v = __hip_atomic_load(&st[ilr[q][x]],
                __ATOMIC_RELAXED, __HIP_MEMORY_SCOPE_WORKGROUP);
            anyK |= (v == 1); allD &= (v != 0);
          }
        }
      } else {                                    // rare: rescan from global
        const int row = rowq[q];
        const int* rp = knn + (long long)row * KNN;
#pragma unroll
        for (int k = 0; k < KNN; ++k) {
          int j = rp[k];
          if (j >= base && j < row) {
            unsigned char v = __hip_atomic_load(&st[j - base],
                __ATOMIC_RELAXED, __HIP_MEMORY_SCOPE_WORKGROUP);
            anyK |= (v == 1); allD &= (v != 0);
          }
        }
      }
      if (anyK)      myst[q] = 2;
      else if (allD) myst[q] = 1;
      if (myst[q] != 0)
        __hip_atomic_store(&st[o], myst[q],
                           __ATOMIC_RELAXED, __HIP_MEMORY_SCOPE_WORKGROUP);
      else
        undec = true;
    }
  }

  // ---- publish: PER-WAVE, immediate (no block barrier before words) ----
  bool kq[QRT];
#pragma unroll
  for (int q = 0; q < QRT; ++q)
    kq[q] = vq[q] && (myst[q] == 1);

  if (b < NCH - 1) {
    const int lane = t & 63;
#pragma unroll
    for (int q = 0; q < QRT; ++q) {
      unsigned long long ba = __ballot(kq[q]);    // rows base+q*1024+(t&~63)+lane
      const int g = b * W64PC + ((q * BLK + (t & ~63)) >> 5);
      if (lane == 0)
        __hip_atomic_store(&bmg64[g], (ba & 0xffffffffull) | VALIDB,
                           __ATOMIC_RELAXED, __HIP_MEMORY_SCOPE_AGENT);
      if (lane == 32)
        __hip_atomic_store(&bmg64[g + 1], (ba >> 32) | VALIDB,
                           __ATOMIC_RELAXED, __HIP_MEMORY_SCOPE_AGENT);
    }
  }
  __syncthreads();                                // all waves' words issued
  if (t == 0)                                     // conservative hint ordering
    __hip_atomic_store(progress, (unsigned int)(b + 1),
                       __ATOMIC_RELAXED, __HIP_MEMORY_SCOPE_AGENT);

  // ---- outputs (off the chain; block 73's knn overwrites dead scratch) ----
#pragma unroll
  for (int q = 0; q < QRT; ++q)
    if (vq[q]) out[rowq[q]] = kq[q] ? 1 : 0;

#pragma unroll
  for (int q = 0; q < QRT; ++q) {
    if (!vq[q]) continue;
    const int row = rowq[q];
    const int* rp = knn + (long long)row * KNN;
    int* orow = out + M_ROWS + (long long)row * KNN;
    const bool k = kq[q];
#pragma unroll
    for (int u = 0; u < 16; ++u) {
      int4 d = ((const int4*)rp)[u];
      int4 o4;
      o4.x = k ? d.x : M_ROWS;
      o4.y = k ? d.y : M_ROWS;
      o4.z = k ? d.z : M_ROWS;
      o4.w = k ? d.w : M_ROWS;
      ((int4*)orow)[u] = o4;
    }
  }
}

extern "C" void kernel_launch(void* const* d_in, const int* in_sizes, int n_in,
                              void* d_out, int out_size, void* d_ws, size_t ws_size,
                              hipStream_t stream) {
  const int* knn = (const int*)d_in[1];
  int* out = (int*)d_out;
  unsigned int* progress = (unsigned int*)d_ws;

  init_ws_kernel<<<(NBMG + BLK - 1) / BLK, BLK, 0, stream>>>(progress, out);
  nms_chain_kernel<<<NCH, BLK, 0, stream>>>(knn, out, progress);
}